// Round 5
// baseline (76.918 us; speedup 1.0000x reference)
//
#include <hip/hip_runtime.h>
#include <hip/hip_bf16.h>
#include <stdint.h>

#define NROWS 8192
#define DDIM  128
#define NCHUNK 16            // column chunks (partial-sum slots)
#define ROWS_PER_BLOCK 128   // 4 waves x 32 rows
#define COLS_PER_BLOCK 512   // NROWS / NCHUNK

typedef __attribute__((ext_vector_type(8))) short short8;
typedef __attribute__((ext_vector_type(4))) float f32x4;

// (1/tau) * log2(e); q is pre-scaled by sqrt of this so exp2(acc) is direct.
#define SCALE 14.426950408889634f

// ---------------- Kernel 1: row-normalize fp32 -> scaled bf16 ------------
__global__ __launch_bounds__(256) void normalize_kernel(
    const float* __restrict__ x, __hip_bfloat16* __restrict__ q)
{
    int wave = threadIdx.x >> 6;
    int lane = threadIdx.x & 63;
    int row  = blockIdx.x * 4 + wave;
    const float* xr = x + (size_t)row * DDIM;
    float a = xr[lane];
    float b = xr[lane + 64];
    float ss = a * a + b * b;
    #pragma unroll
    for (int off = 1; off < 64; off <<= 1)
        ss += __shfl_xor(ss, off, 64);
    float rn = sqrtf(SCALE) / sqrtf(ss);   // fold exp2 scale into q
    q[(size_t)row * DDIM + lane]      = __float2bfloat16(a * rn);
    q[(size_t)row * DDIM + lane + 64] = __float2bfloat16(b * rn);
}

// ---------------- Kernel 2: fused QQ^T + exp + masked row-sums -----------
// grid = 64 row-blocks x 16 col-chunks. Block: 4 waves, 128 rows x 512 cols.
// NO LDS staging for B: each wave reads B fragments straight from L2
// (q = 2 MB, XCD-L2-resident; reads are 1 KB/instruction coalesced).
// No barriers in the hot loop -> waves fully independent.
__global__ __launch_bounds__(256, 4) void sim_kernel(
    const __hip_bfloat16* __restrict__ q, const int* __restrict__ y,
    float* __restrict__ topp, float* __restrict__ downp)
{
    __shared__ int yl[COLS_PER_BLOCK];

    const int bid  = blockIdx.x;
    const int iblk = bid >> 4;
    const int h    = bid & 15;
    const int tid  = threadIdx.x;
    const int wave = tid >> 6;
    const int lane = tid & 63;
    const int lrow = lane & 15;
    const int lhi  = lane >> 4;

    const char* qb = (const char*)q;
    const int rbase = iblk * ROWS_PER_BLOCK + wave * 32;
    const int jbase = h * COLS_PER_BLOCK;

    // stage this chunk's labels into LDS once (single barrier, then none)
    yl[tid]       = y[jbase + tid];
    yl[tid + 256] = y[jbase + tid + 256];

    // A fragments: 2 row-tiles x 4 K-slices (32 VGPRs), loaded once.
    short8 afrag[2][4];
    #pragma unroll
    for (int t = 0; t < 2; ++t)
        #pragma unroll
        for (int ks = 0; ks < 4; ++ks)
            afrag[t][ks] = *(const short8*)(qb +
                (size_t)(rbase + t * 16 + lrow) * 256 + ks * 64 + lhi * 16);

    int yrow[2][4];
    #pragma unroll
    for (int t = 0; t < 2; ++t)
        #pragma unroll
        for (int r = 0; r < 4; ++r)
            yrow[t][r] = y[rbase + t * 16 + lhi * 4 + r];

    __syncthreads();

    float top[2][4]  = {{0.f,0.f,0.f,0.f},{0.f,0.f,0.f,0.f}};
    float down[2][4] = {{0.f,0.f,0.f,0.f},{0.f,0.f,0.f,0.f}};

    #pragma unroll 2
    for (int jt = 0; jt < COLS_PER_BLOCK / 16; ++jt) {
        const int cg = jt * 16 + lrow;
        const char* bsrc = qb + (size_t)(jbase + cg) * 256 + lhi * 16;
        short8 bfrag[4];
        #pragma unroll
        for (int ks = 0; ks < 4; ++ks)
            bfrag[ks] = *(const short8*)(bsrc + ks * 64);
        const int ycol = yl[cg];

        #pragma unroll
        for (int t = 0; t < 2; ++t) {
            f32x4 acc = {0.f, 0.f, 0.f, 0.f};
            #pragma unroll
            for (int ks = 0; ks < 4; ++ks)
                acc = __builtin_amdgcn_mfma_f32_16x16x32_bf16(
                    afrag[t][ks], bfrag[ks], acc, 0, 0, 0);
            #pragma unroll
            for (int r = 0; r < 4; ++r) {
                float e = __builtin_amdgcn_exp2f(acc[r]);
                down[t][r] += e;
                top[t][r]  += (yrow[t][r] == ycol) ? e : 0.0f;
            }
        }
    }

    // reduce across the 16 column-lanes of each group
    #pragma unroll
    for (int m = 1; m < 16; m <<= 1) {
        #pragma unroll
        for (int t = 0; t < 2; ++t)
            #pragma unroll
            for (int r = 0; r < 4; ++r) {
                top[t][r]  += __shfl_xor(top[t][r],  m, 64);
                down[t][r] += __shfl_xor(down[t][r], m, 64);
            }
    }

    if (lrow == 0) {
        #pragma unroll
        for (int t = 0; t < 2; ++t)
            #pragma unroll
            for (int r = 0; r < 4; ++r) {
                int row = rbase + t * 16 + lhi * 4 + r;
                topp [h * NROWS + row] = top[t][r];
                downp[h * NROWS + row] = down[t][r];
            }
    }
}

// ---------------- Kernel 3a: per-row loss, 128-block partial reduce ------
__global__ __launch_bounds__(64) void loss_partial_kernel(
    const float* __restrict__ topp, const float* __restrict__ downp,
    float* __restrict__ partial)
{
    const int lane = threadIdx.x;
    const int r = blockIdx.x * 64 + lane;
    float t = 0.f, d = 0.f;
    #pragma unroll
    for (int hh = 0; hh < NCHUNK; ++hh) {
        t += topp [hh * NROWS + r];
        d += downp[hh * NROWS + r];
    }
    float s = __logf(d) - __logf(t);
    #pragma unroll
    for (int off = 1; off < 64; off <<= 1)
        s += __shfl_xor(s, off, 64);
    if (lane == 0) partial[blockIdx.x] = s;
}

// ---------------- Kernel 3b: final 128 -> scalar -------------------------
__global__ __launch_bounds__(64) void loss_final_kernel(
    const float* __restrict__ partial, float* __restrict__ out)
{
    const int lane = threadIdx.x;
    float s = partial[lane] + partial[lane + 64];
    #pragma unroll
    for (int off = 1; off < 64; off <<= 1)
        s += __shfl_xor(s, off, 64);
    if (lane == 0) out[0] = s / (float)NROWS;
}

extern "C" void kernel_launch(void* const* d_in, const int* in_sizes, int n_in,
                              void* d_out, int out_size, void* d_ws, size_t ws_size,
                              hipStream_t stream)
{
    const float* x = (const float*)d_in[0];
    const int*   y = (const int*)d_in[1];
    float* out = (float*)d_out;

    char* ws = (char*)d_ws;
    __hip_bfloat16* q = (__hip_bfloat16*)ws;                       // 2 MB
    float* topp  = (float*)(ws + (size_t)NROWS * DDIM * 2);        // 512 KB
    float* downp = topp + NCHUNK * NROWS;                          // 512 KB
    float* partial = downp + NCHUNK * NROWS;                       // 512 B

    normalize_kernel<<<NROWS / 4, 256, 0, stream>>>(x, q);
    sim_kernel<<<64 * NCHUNK, 256, 0, stream>>>(q, y, topp, downp);
    loss_partial_kernel<<<NROWS / 64, 64, 0, stream>>>(topp, downp, partial);
    loss_final_kernel<<<1, 64, 0, stream>>>(partial, out);
}

// Round 6
// 36.296 us; speedup vs baseline: 2.1192x; 2.1192x over previous
//
#include <hip/hip_runtime.h>
#include <hip/hip_bf16.h>
#include <stdint.h>

#define NROWS 8192
#define DDIM  128
#define NCHUNK 16            // column chunks (partial-sum slots)
#define ROWS_PER_BLOCK 128   // 4 waves x 32 rows
#define COLS_PER_BLOCK 512   // NROWS / NCHUNK
#define GROUP_COLS 64        // cols staged per LDS buffer
#define GROUP_BYTES (GROUP_COLS * DDIM)       // fp8: 8192 B
#define NGROUPS (COLS_PER_BLOCK / GROUP_COLS) // 8

typedef __attribute__((ext_vector_type(4))) float f32x4;
typedef long f8x8;           // 8 fp8 elements = 8 bytes = 2 VGPRs

__device__ __forceinline__ void load_lds16(const void* g, void* l) {
    __builtin_amdgcn_global_load_lds(
        (const __attribute__((address_space(1))) void*)g,
        (__attribute__((address_space(3))) void*)l, 16, 0, 0);
}

// (1/tau) * log2(e); q is pre-scaled by sqrt of this so exp2(acc) = e^{s/tau}.
#define SCALE 14.426950408889634f
#define E10   22026.465794806718f   // exp(1/tau) exact diagonal term

// ---------- Kernel 1: row-normalize fp32 -> scaled fp8, emit ||q||^2 -----
// block = 256 = 4 waves, one row per wave; lane l handles elems 2l, 2l+1.
__global__ __launch_bounds__(256) void normalize_kernel(
    const float* __restrict__ x, unsigned short* __restrict__ q16,
    float* __restrict__ dsq)
{
    int wave = threadIdx.x >> 6;
    int lane = threadIdx.x & 63;
    int row  = blockIdx.x * 4 + wave;
    const float2* xr = (const float2*)(x + (size_t)row * DDIM);
    float2 v = xr[lane];
    float ss = v.x * v.x + v.y * v.y;
    #pragma unroll
    for (int off = 1; off < 64; off <<= 1)
        ss += __shfl_xor(ss, off, 64);
    float rn = sqrtf(SCALE / ss);
    int pk = __builtin_amdgcn_cvt_pk_fp8_f32(v.x * rn, v.y * rn, 0, false);
    q16[(size_t)row * 64 + lane] = (unsigned short)(pk & 0xffff);
    // exact quantized self-energy (matches what the MFMA diagonal computes)
    float d0 = __builtin_amdgcn_cvt_f32_fp8(pk, 0);
    float d1 = __builtin_amdgcn_cvt_f32_fp8(pk, 1);
    float sq = d0 * d0 + d1 * d1;
    #pragma unroll
    for (int off = 1; off < 64; off <<= 1)
        sq += __shfl_xor(sq, off, 64);
    if (lane == 0) dsq[row] = sq;
}

// ---------- Kernel 2: fused fp8 QQ^T + exp2 + masked row-sums ------------
// grid = 64 row-blocks x 16 col-chunks. Block: 4 waves, 128 rows x 512 cols.
// B staged in LDS (fp8, 64-col groups, double-buffered). Swizzle: logical
// byte (c,k) stored at c*128 + (k ^ ((c&7)<<4)) — bits 4-6 only, so the
// 16B stage granule maps to a contiguous source block (T21-safe) and b64
// reads hit each 8B slot with exactly 4 lanes (= floor, conflict-free).
__global__ __launch_bounds__(256, 4) void sim_kernel(
    const unsigned short* __restrict__ q16, const int* __restrict__ y,
    float* __restrict__ topp, float* __restrict__ downp)
{
    __shared__ char smem[2 * GROUP_BYTES];
    __shared__ int  yl[COLS_PER_BLOCK];

    const int bid  = blockIdx.x;
    const int iblk = bid >> 4;
    const int h    = bid & 15;
    const int tid  = threadIdx.x;
    const int lane = tid & 63;
    const int wave = tid >> 6;
    const int lrow = lane & 15;
    const int lhi  = lane >> 4;

    const char* qb = (const char*)q16;
    const int rbase = iblk * ROWS_PER_BLOCK + wave * 32;
    const int jbase = h * COLS_PER_BLOCK;

    yl[tid]       = y[jbase + tid];
    yl[tid + 256] = y[jbase + tid + 256];

    // A fragments: 2 row-tiles x 4 K-slices, 8B each (16 VGPRs total).
    f8x8 afrag[2][4];
    #pragma unroll
    for (int t = 0; t < 2; ++t)
        #pragma unroll
        for (int ks = 0; ks < 4; ++ks)
            afrag[t][ks] = *(const f8x8*)(qb +
                (size_t)(rbase + t * 16 + lrow) * DDIM + ks * 32 + lhi * 8);

    int yrow[2][4];
    #pragma unroll
    for (int t = 0; t < 2; ++t)
        #pragma unroll
        for (int r = 0; r < 4; ++r)
            yrow[t][r] = y[rbase + t * 16 + lhi * 4 + r];

    float top[2][4]  = {{0.f,0.f,0.f,0.f},{0.f,0.f,0.f,0.f}};
    float down[2][4] = {{0.f,0.f,0.f,0.f},{0.f,0.f,0.f,0.f}};

    // stage group g: linear LDS dest, source pre-swizzled (involution on
    // bits 4-6 keyed by col; granule-safe since bits 0-3 untouched).
    auto stage = [&](int buf, int g) {
        const int jstart = jbase + g * GROUP_COLS;
        #pragma unroll
        for (int p = 0; p < 2; ++p) {
            int phys = p * 4096 + tid * 16;
            int col  = phys >> 7;
            int L    = phys ^ ((col & 7) << 4);
            const char* src = qb + (size_t)(jstart + col) * DDIM + (L & 127);
            load_lds16(src, smem + buf * GROUP_BYTES + phys);
        }
    };

    stage(0, 0);
    __syncthreads();

    for (int g = 0; g < NGROUPS; ++g) {
        if (g + 1 < NGROUPS) stage((g + 1) & 1, g + 1);

        const char* lbuf = smem + (g & 1) * GROUP_BYTES;

        #pragma unroll
        for (int jt = 0; jt < GROUP_COLS / 16; ++jt) {
            const int cg = jt * 16 + lrow;
            const int ycol = yl[g * GROUP_COLS + cg];
            f8x8 bfrag[4];
            #pragma unroll
            for (int ks = 0; ks < 4; ++ks) {
                int off = cg * DDIM + ((ks * 32 + lhi * 8) ^ ((cg & 7) << 4));
                bfrag[ks] = *(const f8x8*)(lbuf + off);
            }
            #pragma unroll
            for (int t = 0; t < 2; ++t) {
                f32x4 acc = {0.f, 0.f, 0.f, 0.f};
                #pragma unroll
                for (int ks = 0; ks < 4; ++ks)
                    acc = __builtin_amdgcn_mfma_f32_16x16x32_fp8_fp8(
                        afrag[t][ks], bfrag[ks], acc, 0, 0, 0);
                #pragma unroll
                for (int r = 0; r < 4; ++r) {
                    float e = __builtin_amdgcn_exp2f(acc[r]);
                    down[t][r] += e;
                    top[t][r]  += (yrow[t][r] == ycol) ? e : 0.0f;
                }
            }
        }
        __syncthreads();
    }

    #pragma unroll
    for (int m = 1; m < 16; m <<= 1) {
        #pragma unroll
        for (int t = 0; t < 2; ++t)
            #pragma unroll
            for (int r = 0; r < 4; ++r) {
                top[t][r]  += __shfl_xor(top[t][r],  m, 64);
                down[t][r] += __shfl_xor(down[t][r], m, 64);
            }
    }

    if (lrow == 0) {
        #pragma unroll
        for (int t = 0; t < 2; ++t)
            #pragma unroll
            for (int r = 0; r < 4; ++r) {
                int row = rbase + t * 16 + lhi * 4 + r;
                topp [h * NROWS + row] = top[t][r];
                downp[h * NROWS + row] = down[t][r];
            }
    }
}

// ---------- Kernel 3a: per-row loss with exact-diagonal correction -------
__global__ __launch_bounds__(64) void loss_partial_kernel(
    const float* __restrict__ topp, const float* __restrict__ downp,
    const float* __restrict__ dsq, float* __restrict__ partial)
{
    const int lane = threadIdx.x;
    const int r = blockIdx.x * 64 + lane;
    float t = 0.f, d = 0.f;
    #pragma unroll
    for (int hh = 0; hh < NCHUNK; ++hh) {
        t += topp [hh * NROWS + r];
        d += downp[hh * NROWS + r];
    }
    // replace quantized diagonal exp2(||q||^2) with exact e^{1/tau}
    float e2d = __builtin_amdgcn_exp2f(dsq[r]);
    t = t - e2d + E10;
    d = d - e2d + E10;
    float s = __logf(d) - __logf(t);
    #pragma unroll
    for (int off = 1; off < 64; off <<= 1)
        s += __shfl_xor(s, off, 64);
    if (lane == 0) partial[blockIdx.x] = s;
}

// ---------- Kernel 3b: final 128 -> scalar -------------------------------
__global__ __launch_bounds__(64) void loss_final_kernel(
    const float* __restrict__ partial, float* __restrict__ out)
{
    const int lane = threadIdx.x;
    float s = partial[lane] + partial[lane + 64];
    #pragma unroll
    for (int off = 1; off < 64; off <<= 1)
        s += __shfl_xor(s, off, 64);
    if (lane == 0) out[0] = s / (float)NROWS;
}

extern "C" void kernel_launch(void* const* d_in, const int* in_sizes, int n_in,
                              void* d_out, int out_size, void* d_ws, size_t ws_size,
                              hipStream_t stream)
{
    const float* x = (const float*)d_in[0];
    const int*   y = (const int*)d_in[1];
    float* out = (float*)d_out;

    char* ws = (char*)d_ws;
    unsigned short* q16 = (unsigned short*)ws;                     // 1 MB fp8
    float* topp  = (float*)(ws + (size_t)NROWS * DDIM);            // 512 KB
    float* downp = topp + NCHUNK * NROWS;                          // 512 KB
    float* dsq     = downp + NCHUNK * NROWS;                       // 32 KB
    float* partial = dsq + NROWS;                                  // 512 B

    normalize_kernel<<<NROWS / 4, 256, 0, stream>>>(x, q16, dsq);
    sim_kernel<<<64 * NCHUNK, 256, 0, stream>>>(q16, y, topp, downp);
    loss_partial_kernel<<<NROWS / 64, 64, 0, stream>>>(topp, downp, dsq, partial);
    loss_final_kernel<<<1, 64, 0, stream>>>(partial, out);
}